// Round 1
// baseline (766.255 us; speedup 1.0000x reference)
//
#include <hip/hip_runtime.h>

#define NCAM 6
#define FC   128
#define FH_  32
#define FW_  88
#define NPIX (FH_*FW_)        // 2816
#define ND   41
#define X3C  170              // 41 depth + 1 opacity + 128 feat
#define OUTC 128
#define GTOT (NCAM*NPIX)      // 16896
#define BEVH 100
#define BEVW 100
#define NPXB (BEVH*BEVW)      // 10000

// ---- ws layout (float offsets) ----
#define WS_CAM    0                          // 6*24 = 144 floats
#define WS_X1     256
#define WS_X2     (WS_X1 + NCAM*FC*NPIX)     // +2162688
#define WS_X3     (WS_X2 + NCAM*FC*NPIX)
#define WS_GAUSS  (WS_X3 + NCAM*X3C*NPIX)
#define WS_COLORS WS_X1                      // X1 is dead after conv2; reuse (same size)

__device__ inline void inv3x3(const float* m, float* o) {
    float a=m[0],b=m[1],c=m[2],d=m[3],e=m[4],f=m[5],g=m[6],h=m[7],i=m[8];
    float A=e*i-f*h, B=c*h-b*i, C=b*f-c*e;
    float Dd=f*g-d*i, E=a*i-c*g, F=c*d-a*f;
    float Gg=d*h-e*g, H=b*g-a*h, I=a*e-b*d;
    float r = 1.0f/(a*A + b*Dd + c*Gg);
    o[0]=A*r; o[1]=B*r; o[2]=C*r; o[3]=Dd*r; o[4]=E*r; o[5]=F*r;
    o[6]=Gg*r; o[7]=H*r; o[8]=I*r;
}

// per-camera: M1 = inv(post_rot) [0..8], t1 = post_trans [9..11],
//             comb = rot@inv(K)  [12..20], t2 = trans [21..23]
__global__ void cam_consts_kernel(const float* __restrict__ rot, const float* __restrict__ tr,
                                  const float* __restrict__ intr, const float* __restrict__ prot,
                                  const float* __restrict__ ptr_, float* __restrict__ cam) {
    int n = threadIdx.x;
    if (n >= NCAM) return;
    float M1[9], Ki[9];
    inv3x3(prot + n*9, M1);
    inv3x3(intr + n*9, Ki);
    const float* R = rot + n*9;
    float* c = cam + n*24;
    for (int i=0;i<9;i++) c[i] = M1[i];
    for (int i=0;i<3;i++) c[9+i] = ptr_[n*3+i];
    for (int i=0;i<3;i++)
        for (int j=0;j<3;j++)
            c[12+i*3+j] = R[i*3+0]*Ki[0+j] + R[i*3+1]*Ki[3+j] + R[i*3+2]*Ki[6+j];
    for (int i=0;i<3;i++) c[21+i] = tr[n*3+i];
}

// direct 3x3 conv + folded BN + ReLU. grid (NCAM, 32 co-groups of 4, 4 pixel chunks of 768)
__global__ __launch_bounds__(256) void conv3x3_bn_relu_kernel(
        const float* __restrict__ in, float* __restrict__ out, const float* __restrict__ w,
        const float* __restrict__ cb, const float* __restrict__ bg, const float* __restrict__ bb,
        const float* __restrict__ bm, const float* __restrict__ bv) {
    const int n   = blockIdx.x;
    const int co0 = blockIdx.y * 4;
    const int t   = threadIdx.x;
    const int pbase = blockIdx.z * 768;
    float scale[4], shift[4];
    #pragma unroll
    for (int c=0;c<4;c++) {
        float s = bg[co0+c] * rsqrtf(bv[co0+c] + 1e-3f);
        scale[c] = s;
        shift[c] = (cb[co0+c] - bm[co0+c]) * s + bb[co0+c];
    }
    int hh[3], xx[3];
    #pragma unroll
    for (int k=0;k<3;k++) { int p = pbase + k*256 + t; hh[k] = p/FW_; xx[k] = p - hh[k]*FW_; }
    float acc[4][3] = {};
    const float* ib = in + (size_t)n*FC*NPIX;
    const float* wb = w  + (size_t)co0*FC*9;
    for (int ci=0; ci<FC; ++ci) {
        const float* ip = ib + (size_t)ci*NPIX;
        float wr[4][9];
        #pragma unroll
        for (int c=0;c<4;c++)
            #pragma unroll
            for (int k=0;k<9;k++) wr[c][k] = wb[(size_t)c*FC*9 + ci*9 + k];
        #pragma unroll
        for (int k=0;k<3;k++) {
            float v[9];
            #pragma unroll
            for (int dy=0;dy<3;dy++) {
                int y = hh[k] + dy - 1;
                bool yok = (unsigned)y < (unsigned)FH_;
                #pragma unroll
                for (int dx=0;dx<3;dx++) {
                    int x = xx[k] + dx - 1;
                    v[dy*3+dx] = (yok && (unsigned)x < (unsigned)FW_) ? ip[y*FW_ + x] : 0.0f;
                }
            }
            #pragma unroll
            for (int c=0;c<4;c++) {
                float a = acc[c][k];
                a = fmaf(wr[c][0], v[0], a); a = fmaf(wr[c][1], v[1], a);
                a = fmaf(wr[c][2], v[2], a); a = fmaf(wr[c][3], v[3], a);
                a = fmaf(wr[c][4], v[4], a); a = fmaf(wr[c][5], v[5], a);
                a = fmaf(wr[c][6], v[6], a); a = fmaf(wr[c][7], v[7], a);
                a = fmaf(wr[c][8], v[8], a);
                acc[c][k] = a;
            }
        }
    }
    #pragma unroll
    for (int k=0;k<3;k++) {
        int p = pbase + k*256 + t;
        if (p < NPIX) {
            #pragma unroll
            for (int c=0;c<4;c++)
                out[((size_t)n*FC + co0 + c)*NPIX + p] = fmaxf(fmaf(acc[c][k], scale[c], shift[c]), 0.0f);
        }
    }
}

// 1x1 conv (conv3). grid (NCAM, 43 co-groups of 4, 4 pixel chunks)
__global__ __launch_bounds__(256) void conv1x1_kernel(const float* __restrict__ in,
        float* __restrict__ out, const float* __restrict__ w, const float* __restrict__ b) {
    const int n   = blockIdx.x;
    const int co0 = blockIdx.y * 4;
    const int t   = threadIdx.x;
    const int pbase = blockIdx.z * 768;
    float acc[4][3];
    #pragma unroll
    for (int c=0;c<4;c++) {
        float bias = (co0+c < X3C) ? b[co0+c] : 0.0f;
        #pragma unroll
        for (int k=0;k<3;k++) acc[c][k] = bias;
    }
    const float* ib = in + (size_t)n*FC*NPIX;
    for (int ci=0; ci<FC; ++ci) {
        float wr[4];
        #pragma unroll
        for (int c=0;c<4;c++) wr[c] = (co0+c < X3C) ? w[(size_t)(co0+c)*FC + ci] : 0.0f;
        #pragma unroll
        for (int k=0;k<3;k++) {
            int p = pbase + k*256 + t;
            float v = (p < NPIX) ? ib[(size_t)ci*NPIX + p] : 0.0f;
            #pragma unroll
            for (int c=0;c<4;c++) acc[c][k] = fmaf(wr[c], v, acc[c][k]);
        }
    }
    #pragma unroll
    for (int k=0;k<3;k++) {
        int p = pbase + k*256 + t;
        if (p < NPIX) {
            #pragma unroll
            for (int c=0;c<4;c++)
                if (co0+c < X3C) out[((size_t)n*X3C + co0+c)*NPIX + p] = acc[c][k];
        }
    }
}

// per-gaussian: softmax over depth, xy moments (geometry computed inline),
// splat precompute {my,mx,A,B,C,qm,ri,rj}; count opacity mask.
__global__ __launch_bounds__(256) void moments_kernel(const float* __restrict__ x3,
        const float* __restrict__ cam, float* __restrict__ gauss, float* __restrict__ ng) {
    int gi = blockIdx.x*256 + threadIdx.x;            // 66*256 == 16896 exactly
    int n  = gi / NPIX;
    int p  = gi - n*NPIX;
    int h  = p / FW_, xp = p - h*FW_;
    const float* cc = cam + n*24;
    float u = xp * (703.0f/87.0f);
    float v = h  * (255.0f/31.0f);
    float fx = u - cc[9], fy = v - cc[10], fz = -cc[11];
    float p0x = cc[0]*fx + cc[1]*fy + cc[2]*fz;
    float p0y = cc[3]*fx + cc[4]*fy + cc[5]*fz;
    float p0z = cc[6]*fx + cc[7]*fy + cc[8]*fz;
    const float* lg = x3 + (size_t)n*X3C*NPIX + p;

    float mxl = -1e30f;
    for (int d=0; d<ND; ++d) mxl = fmaxf(mxl, lg[(size_t)d*NPIX]);
    float s=0.f, sgx=0.f, sgy=0.f;
    for (int d=0; d<ND; ++d) {
        float e  = __expf(lg[(size_t)d*NPIX] - mxl);
        float dz = 4.0f + (float)d;
        float pz = p0z + dz*cc[8];
        float px = (p0x + dz*cc[2]) * pz;
        float py = (p0y + dz*cc[5]) * pz;
        float gx = cc[12]*px + cc[13]*py + cc[14]*pz + cc[21];
        float gy = cc[15]*px + cc[16]*py + cc[17]*pz + cc[22];
        s += e; sgx += e*gx; sgy += e*gy;
    }
    float inv_s = 1.0f/s;
    float mex = sgx*inv_s, mey = sgy*inv_s;
    float cxx=0.f, cxy=0.f, cyy=0.f;
    for (int d=0; d<ND; ++d) {
        float e  = __expf(lg[(size_t)d*NPIX] - mxl);
        float dz = 4.0f + (float)d;
        float pz = p0z + dz*cc[8];
        float px = (p0x + dz*cc[2]) * pz;
        float py = (p0y + dz*cc[5]) * pz;
        float gx = cc[12]*px + cc[13]*py + cc[14]*pz + cc[21];
        float gy = cc[15]*px + cc[16]*py + cc[17]*pz + cc[22];
        float dxv = gx - mex, dyv = gy - mey;
        cxx += e*dxv*dxv; cxy += e*dxv*dyv; cyy += e*dyv*dyv;
    }
    const float k9 = inv_s * (1.0f/9.0f);
    cxx *= k9; cxy *= k9; cyy *= k9;

    float lo = lg[(size_t)ND*NPIX];
    float op = 1.0f/(1.0f + __expf(-lo));
    bool mask = op > 0.05f;

    const float SC = 0.02f, SH = 50.0f, SW = 50.0f;
    float my = -SH*(mey*SC) + 50.0f;
    float mx = -SW*(mex*SC) + 50.0f;
    float a  = SH*SH*(cyy*SC*SC) + 0.3f;   // row (i) variance
    float b  = SH*SW*(cxy*SC*SC);
    float c  = SW*SW*(cxx*SC*SC) + 0.3f;   // col (j) variance
    float det = a*c - b*b;
    bool valid = mask && (det > 0.0f);
    float A, Bc, C, qm, ri, rj;
    if (valid) {
        float idet = 1.0f/det;
        A = c*idet; Bc = -b*idet; C = a*idet;
        qm = 2.0f*__logf(255.0f*op);       // alpha>=1/255  <=>  q<=qm  (op>0.05 => qm>5)
        ri = sqrtf(qm*a); rj = sqrtf(qm*c);
    } else { A=Bc=C=0.f; qm=-1.0f; ri=-1e30f; rj=-1e30f; }
    float* gp = gauss + (size_t)gi*8;
    gp[0]=my; gp[1]=mx; gp[2]=A; gp[3]=Bc; gp[4]=C; gp[5]=qm; gp[6]=ri; gp[7]=rj;

    unsigned long long bal = __ballot(mask);
    if ((threadIdx.x & 63) == 0) atomicAdd(ng, (float)__popcll(bal));
}

// x3 feature planes [n][42+c][p]  ->  colors [g][128], LDS-tiled transpose
__global__ __launch_bounds__(256) void transpose_kernel(const float* __restrict__ x3,
                                                        float* __restrict__ colors) {
    __shared__ float lds[128*65];
    const int n  = blockIdx.y;
    const int p0 = blockIdx.x * 64;           // 44 tiles * 64 = 2816
    const int t  = threadIdx.x;
    const int cq = t >> 6, pp = t & 63;
    const float* src = x3 + (size_t)n*X3C*NPIX + (size_t)(ND+1)*NPIX + p0;
    for (int c = cq; c < OUTC; c += 4)
        lds[c*65 + pp] = src[(size_t)c*NPIX + pp];
    __syncthreads();
    for (int it = 0; it < 32; ++it) {
        int idx = it*256 + t;
        int c   = idx & 127;
        int pq  = idx >> 7;
        colors[((size_t)(n*NPIX + p0 + pq) << 7) + c] = lds[c*65 + pq];
    }
}

// ordered compositing: 1250 blocks x 8 px (2 rows x 4 cols). batch 256 gaussians,
// one gaussian per lane in phase A, ordered bit-walk in phase B.
__global__ __launch_bounds__(256) void splat_kernel(const float* __restrict__ gauss,
        const float* __restrict__ colors, float* __restrict__ out) {
    __shared__ __align__(16) float s_alpha[256][8];
    __shared__ unsigned long long s_hm[4];
    const int t    = threadIdx.x;
    const int wave = t >> 6;
    const int lane = t & 63;
    const int bi = blockIdx.x / 25, bj = blockIdx.x % 25;
    const int i0 = bi*2, j0 = bj*4;
    const float ic = i0 + 0.5f, jc = j0 + 1.5f;
    const int pxB = t >> 5;                 // 0..7
    const int c4  = (t & 31) << 2;          // channel base
    float T = 1.0f;
    float4 acc = make_float4(0.f,0.f,0.f,0.f);

    for (int gbase = 0; gbase < GTOT; gbase += 256) {
        // ---- phase A: one gaussian per thread ----
        const int g = gbase + t;
        const float4* gp = (const float4*)(gauss + ((size_t)g << 3));
        float4 g0 = gp[0];   // my, mx, A, B
        float4 g1 = gp[1];   // C, qm, ri, rj
        bool anyhit = false;
        if (fabsf(ic - g0.x) <= 0.5f + g1.z && fabsf(jc - g0.y) <= 1.5f + g1.w) {
            float a8[8];
            #pragma unroll
            for (int px=0; px<8; ++px) {
                float dI = (float)(i0 + (px>>2)) - g0.x;
                float dJ = (float)(j0 + (px&3)) - g0.y;
                float q  = dI*(g0.z*dI + 2.0f*g0.w*dJ) + g1.x*dJ*dJ;
                float al = 0.0f;
                if (q >= 0.0f && q <= g1.y) {
                    al = fminf(0.99f, 0.003921568627f * __expf(0.5f*(g1.y - q)));
                    anyhit = true;
                }
                a8[px] = al;
            }
            *(float4*)&s_alpha[t][0] = make_float4(a8[0],a8[1],a8[2],a8[3]);
            *(float4*)&s_alpha[t][4] = make_float4(a8[4],a8[5],a8[6],a8[7]);
        }
        unsigned long long m = __ballot(anyhit);
        if (lane == 0) s_hm[wave] = m;
        __syncthreads();
        // ---- phase B: walk hit bits in gaussian-index order ----
        #pragma unroll
        for (int w2 = 0; w2 < 4; ++w2) {
            unsigned long long m2 = s_hm[w2];
            while (m2) {
                int b = __builtin_ctzll(m2);
                m2 &= (m2 - 1);
                int gl = (w2<<6) + b;
                float al = s_alpha[gl][pxB];
                if (al > 0.0f) {
                    float wgt = al * T;
                    T -= wgt;                               // T *= (1 - al)
                    const float4 col = *(const float4*)(colors + (((size_t)(gbase + gl)) << 7) + c4);
                    acc.x = fmaf(wgt, col.x, acc.x);
                    acc.y = fmaf(wgt, col.y, acc.y);
                    acc.z = fmaf(wgt, col.z, acc.z);
                    acc.w = fmaf(wgt, col.w, acc.w);
                }
            }
        }
        __syncthreads();
    }
    const int pix = (i0 + (pxB>>2))*BEVW + (j0 + (pxB&3));
    out[(size_t)(c4+0)*NPXB + pix] = acc.x;
    out[(size_t)(c4+1)*NPXB + pix] = acc.y;
    out[(size_t)(c4+2)*NPXB + pix] = acc.z;
    out[(size_t)(c4+3)*NPXB + pix] = acc.w;
}

extern "C" void kernel_launch(void* const* d_in, const int* in_sizes, int n_in,
                              void* d_out, int out_size, void* d_ws, size_t ws_size,
                              hipStream_t stream) {
    const float* rot  = (const float*)d_in[0];
    const float* tr   = (const float*)d_in[1];
    const float* intr = (const float*)d_in[2];
    const float* prot = (const float*)d_in[3];
    const float* ptr_ = (const float*)d_in[4];
    const float* img  = (const float*)d_in[5];
    const float* c1w  = (const float*)d_in[6];  const float* c1b = (const float*)d_in[7];
    const float* b1g  = (const float*)d_in[8];  const float* b1b = (const float*)d_in[9];
    const float* b1m  = (const float*)d_in[10]; const float* b1v = (const float*)d_in[11];
    const float* c2w  = (const float*)d_in[12]; const float* c2b = (const float*)d_in[13];
    const float* b2g  = (const float*)d_in[14]; const float* b2b = (const float*)d_in[15];
    const float* b2m  = (const float*)d_in[16]; const float* b2v = (const float*)d_in[17];
    const float* c3w  = (const float*)d_in[18]; const float* c3b = (const float*)d_in[19];
    float* out = (float*)d_out;
    float* ws  = (float*)d_ws;
    float* CAM = ws + WS_CAM;
    float* X1  = ws + WS_X1;
    float* X2  = ws + WS_X2;
    float* X3  = ws + WS_X3;
    float* GS  = ws + WS_GAUSS;
    float* COL = ws + WS_COLORS;
    float* ngp = out + (size_t)NPXB*OUTC;     // num_gaussians scalar (output 1)

    cam_consts_kernel<<<1, 64, 0, stream>>>(rot, tr, intr, prot, ptr_, CAM);
    conv3x3_bn_relu_kernel<<<dim3(NCAM,32,4), 256, 0, stream>>>(img, X1, c1w, c1b, b1g, b1b, b1m, b1v);
    conv3x3_bn_relu_kernel<<<dim3(NCAM,32,4), 256, 0, stream>>>(X1, X2, c2w, c2b, b2g, b2b, b2m, b2v);
    conv1x1_kernel<<<dim3(NCAM,43,4), 256, 0, stream>>>(X2, X3, c3w, c3b);
    hipMemsetAsync(ngp, 0, sizeof(float), stream);
    moments_kernel<<<GTOT/256, 256, 0, stream>>>(X3, CAM, GS, ngp);
    transpose_kernel<<<dim3(44, NCAM), 256, 0, stream>>>(X3, COL);
    splat_kernel<<<1250, 256, 0, stream>>>(GS, COL, out);
}